// Round 6
// baseline (292.585 us; speedup 1.0000x reference)
//
#include <hip/hip_runtime.h>
#include <hip/hip_bf16.h>
#include <stdint.h>

#define M_DIM 8192   // 4*2048
#define N_DIM 4096   // OUT_FEATURES
#define K_DIM 4096   // IN_FEATURES
#define KB2   (K_DIM * 2)   // bytes per K-row

typedef __attribute__((ext_vector_type(8)))  __bf16 bf16x8;
typedef __attribute__((ext_vector_type(4)))  float  f32x4;
typedef __attribute__((ext_vector_type(16))) float  f32x16;

#define GLD_LDS16(gaddr, laddr)                                            \
  __builtin_amdgcn_global_load_lds(                                        \
      (const __attribute__((address_space(1))) uint32_t*)(gaddr),          \
      (__attribute__((address_space(3))) uint32_t*)(laddr), 16, 0, 0)

// ---------------------------------------------------------------------------
// Dequant: qweight (8, O, 128) int32 bit-planes + lut (O,16) -> Wb (O,K) bf16
// ---------------------------------------------------------------------------
__global__ __launch_bounds__(256) void anyprec_dequant_kernel(
    const int* __restrict__ q, const float* __restrict__ lut,
    __bf16* __restrict__ Wb) {
  int t = blockIdx.x * 256 + threadIdx.x;   // 0 .. O*128-1
  int o = t >> 7;
  int w = t & 127;
  const int PLANE = N_DIM * (K_DIM / 32);
  int base = o * (K_DIM / 32) + w;
  uint32_t q0 = (uint32_t)q[0 * PLANE + base];
  uint32_t q1 = (uint32_t)q[1 * PLANE + base];
  uint32_t q2 = (uint32_t)q[2 * PLANE + base];
  uint32_t q3 = (uint32_t)q[3 * PLANE + base];
  const float* lrow = lut + o * 16;

  __bf16 vals[32];
#pragma unroll
  for (int i = 0; i < 32; ++i) {
    uint32_t idx = ((q0 >> i) & 1u) | (((q1 >> i) & 1u) << 1) |
                   (((q2 >> i) & 1u) << 2) | (((q3 >> i) & 1u) << 3);
    vals[i] = (__bf16)lrow[idx];
  }
  bf16x8* dst = (bf16x8*)(Wb + (size_t)o * K_DIM + w * 32);
#pragma unroll
  for (int r = 0; r < 4; ++r) {
    bf16x8 v;
#pragma unroll
    for (int j = 0; j < 8; ++j) v[j] = vals[r * 8 + j];
    dst[r] = v;
  }
}

// ---------------------------------------------------------------------------
// x fp32 -> bf16
// ---------------------------------------------------------------------------
__global__ __launch_bounds__(256) void cvt_x_kernel(
    const float* __restrict__ x, __bf16* __restrict__ xb, int n8) {
  int t = blockIdx.x * 256 + threadIdx.x;
  if (t >= n8) return;
  f32x4 a = ((const f32x4*)x)[t * 2];
  f32x4 b = ((const f32x4*)x)[t * 2 + 1];
  bf16x8 v;
  v[0] = (__bf16)a[0]; v[1] = (__bf16)a[1]; v[2] = (__bf16)a[2]; v[3] = (__bf16)a[3];
  v[4] = (__bf16)b[0]; v[5] = (__bf16)b[1]; v[6] = (__bf16)b[2]; v[7] = (__bf16)b[3];
  ((bf16x8*)xb)[t] = v;
}

// ---------------------------------------------------------------------------
// 256x256 bf16 GEMM, 8-phase register-pipelined, 32x32x16 MFMA (R6).
// 512 thr = 8 waves (2M x 4N); per-wave out 128x64 as 2qm x 2qn quadrants of
// 64x32 (2 mf of 32x32). Reads for phase p+1 issue inside phase p.
// Read balance 4/8/8/4 per phase; stages 1/phase; vmcnt(4) certs at p3/p7.
// ---------------------------------------------------------------------------
__global__ __launch_bounds__(512, 2) void anyprec_gemm_kernel(
    const __bf16* __restrict__ A,   // M x K bf16
    const __bf16* __restrict__ B,   // N x K bf16
    const float* __restrict__ bias,
    float* __restrict__ C) {
  __shared__ __bf16 lds[2][2][2][128 * 64];   // 131072 B

  // XCD-aware bijective swizzle (512 wgs, 512%8==0)
  int bid = blockIdx.x;
  int swz = (bid & 7) * 64 + (bid >> 3);
  int mb = swz >> 4;    // 32 m-tiles
  int nb = swz & 15;    // 16 n-tiles

  const int tid  = threadIdx.x;
  const int lane = tid & 63;
  const int wid  = tid >> 6;
  const int wr   = wid >> 2;   // 0..1
  const int wc   = wid & 3;    // 0..3

  const char* gA = (const char*)A + (size_t)mb * 256 * KB2;
  const char* gB = (const char*)B + (size_t)nb * 256 * KB2;
  const size_t gro0 = (size_t)(tid >> 3) * KB2;       // row  = chunk>>3
  const size_t gro1 = gro0 + (size_t)64 * KB2;        // row + 64
  const int    scx  = (((tid & 7) ^ ((tid >> 3) & 7)) << 4);  // swizzled src chunk
  const int    lt0  = tid * 16;
  const int    lt1  = tid * 16 + 8192;

  // 32x32x16 fragment addressing: row/col = lane&31, k-half = lane>>5
  const int lrow  = lane & 31;
  const int khalf = lane >> 5;
  const int lx7   = lane & 7;
  const int aoffA = (wr * 64 + lrow) * 128;
  const int boffB = (wc * 32 + lrow) * 128;
  int koff[4];
#pragma unroll
  for (int ks = 0; ks < 4; ++ks) koff[ks] = ((ks * 2 + khalf) ^ lx7) << 4;

  f32x16 acc[2][2][2];
#pragma unroll
  for (int qm = 0; qm < 2; ++qm)
#pragma unroll
    for (int qn = 0; qn < 2; ++qn)
#pragma unroll
      for (int mf = 0; mf < 2; ++mf) acc[qm][qn][mf] = (f32x16)0.0f;

  bf16x8 a0[2][4], a1[2][4], b0[4], b1[4];

#define STAGE(mat, h, buf, t) {                                            \
    char* lb_ = (char*)&lds[buf][mat][h][0];                               \
    const char* gb_ = (mat ? gB : gA) + (size_t)(h) * 128 * KB2            \
                      + (size_t)(t) * 128;                                 \
    GLD_LDS16(gb_ + gro0 + scx, lb_ + lt0);                                \
    GLD_LDS16(gb_ + gro1 + scx, lb_ + lt1); }

#define LDA(dst, qm, buf) {                                                \
    const char* p_ = (const char*)&lds[buf][0][qm][0] + aoffA;             \
    _Pragma("unroll")                                                      \
    for (int mf = 0; mf < 2; ++mf)                                         \
      _Pragma("unroll")                                                    \
      for (int ks = 0; ks < 4; ++ks)                                       \
        dst[mf][ks] = *(const bf16x8*)(p_ + mf * 4096 + koff[ks]); }

#define LDB(dst, qn, buf) {                                                \
    const char* p_ = (const char*)&lds[buf][1][qn][0] + boffB;             \
    _Pragma("unroll")                                                      \
    for (int ks = 0; ks < 4; ++ks)                                         \
      dst[ks] = *(const bf16x8*)(p_ + koff[ks]); }

#define MMA(qm, qn, aa, bb) {                                              \
    _Pragma("unroll")                                                      \
    for (int ks = 0; ks < 4; ++ks)                                         \
      _Pragma("unroll")                                                    \
      for (int mf = 0; mf < 2; ++mf)                                       \
        acc[qm][qn][mf] = __builtin_amdgcn_mfma_f32_32x32x16_bf16(         \
            aa[mf][ks], bb[ks], acc[qm][qn][mf], 0, 0, 0); }

#define PRIO1 __builtin_amdgcn_s_setprio(1);
#define PRIO0 __builtin_amdgcn_s_setprio(0);
#define BAR   __builtin_amdgcn_s_barrier();
#define VMC4  asm volatile("s_waitcnt vmcnt(4)" ::: "memory");
#define VMC0  asm volatile("s_waitcnt vmcnt(0)" ::: "memory");
#define VMC6  asm volatile("s_waitcnt vmcnt(6)" ::: "memory");

  // ---- prologue: stage tile0 + A0,B1,A1 of tile1; certify tile0; preload regs
  STAGE(0, 0, 0, 0);  // A0(0)
  STAGE(1, 0, 0, 0);  // B0(0)
  STAGE(1, 1, 0, 0);  // B1(0)
  STAGE(0, 1, 0, 0);  // A1(0)
  STAGE(0, 0, 1, 1);  // A0(1)
  STAGE(1, 1, 1, 1);  // B1(1)
  STAGE(0, 1, 1, 1);  // A1(1)
  VMC6; BAR;
  LDA(a0, 0, 0); LDB(b0, 0, 0);   // consumed in p1

  // ---- main loop: tiles E=2i (buf0), O=2i+1 (buf1), i = 0..30
  for (int i = 0; i < 31; ++i) {
    const int t1 = 2 * i + 1, t2 = 2 * i + 2, t3 = 2 * i + 3;
    // p1: MMA(0,0)E ; load B1(E) [4] ; stage B0(O)
    STAGE(1, 0, 1, t1);
    PRIO1; LDB(b1, 1, 0); MMA(0, 0, a0, b0); PRIO0; BAR;
    // p2: MMA(0,1)E ; load A1(E) [8] ; stage A0(E+2)
    STAGE(0, 0, 0, t2);
    PRIO1; LDA(a1, 1, 0); MMA(0, 1, a0, b1); PRIO0; BAR;
    // p3: MMA(1,1)E ; certify tile O ; load A0(O) [8] ; stage B1(E+2)
    STAGE(1, 1, 0, t2);
    VMC4;
    PRIO1; LDA(a0, 0, 1); MMA(1, 1, a1, b1); PRIO0; BAR;
    // p4: MMA(1,0)E ; load B0(O) [4, after use: WAR] ; stage A1(E+2)
    STAGE(0, 1, 0, t2);
    PRIO1; MMA(1, 0, a1, b0); LDB(b0, 0, 1); PRIO0; BAR;
    // p5: MMA(0,0)O ; load B1(O) [4] ; stage B0(E+2)
    STAGE(1, 0, 0, t2);
    PRIO1; LDB(b1, 1, 1); MMA(0, 0, a0, b0); PRIO0; BAR;
    // p6: MMA(0,1)O ; load A1(O) [8] ; stage A0(O+2)
    STAGE(0, 0, 1, t3);
    PRIO1; LDA(a1, 1, 1); MMA(0, 1, a0, b1); PRIO0; BAR;
    // p7: MMA(1,1)O ; certify tile E+2 ; load A0(E+2) [8] ; stage B1(O+2)
    STAGE(1, 1, 1, t3);
    VMC4;
    PRIO1; LDA(a0, 0, 0); MMA(1, 1, a1, b1); PRIO0; BAR;
    // p8: MMA(1,0)O ; load B0(E+2) [4] ; stage A1(O+2)
    STAGE(0, 1, 1, t3);
    PRIO1; MMA(1, 0, a1, b0); LDB(b0, 0, 0); PRIO0; BAR;
  }

  // ---- tail: tiles 62 (buf0), 63 (buf1); regs hold a0,b0 of 62;
  //      outstanding stages: A0(63),B1(63),A1(63)
  STAGE(1, 0, 1, 63);                         // B0(63)
  PRIO1; LDB(b1, 1, 0); MMA(0, 0, a0, b0); PRIO0; BAR;
  PRIO1; LDA(a1, 1, 0); MMA(0, 1, a0, b1); PRIO0; BAR;
  VMC0;                                       // tile 63 fully resident
  PRIO1; LDA(a0, 0, 1); MMA(1, 1, a1, b1); PRIO0; BAR;
  PRIO1; MMA(1, 0, a1, b0); LDB(b0, 0, 1); PRIO0; BAR;
  PRIO1; LDB(b1, 1, 1); MMA(0, 0, a0, b0); PRIO0; BAR;
  PRIO1; LDA(a1, 1, 1); MMA(0, 1, a0, b1); PRIO0; BAR;
  MMA(1, 1, a1, b1);
  MMA(1, 0, a1, b0);

  // ---- epilogue: 32x32 C/D layout: col=lane&31, row=(j&3)+8*(j>>2)+4*khalf
  const int cL = lane & 31;
#pragma unroll
  for (int qn = 0; qn < 2; ++qn) {
    int col = nb * 256 + qn * 128 + wc * 32 + cL;
    float bv = bias[col];
#pragma unroll
    for (int qm = 0; qm < 2; ++qm)
#pragma unroll
      for (int mf = 0; mf < 2; ++mf) {
        int row0 = mb * 256 + qm * 128 + wr * 64 + mf * 32 + khalf * 4;
#pragma unroll
        for (int j = 0; j < 16; ++j) {
          int row = row0 + (j & 3) + 8 * (j >> 2);
          C[(size_t)row * N_DIM + col] = acc[qm][qn][mf][j] + bv;
        }
      }
  }
#undef STAGE
#undef LDA
#undef LDB
#undef MMA
#undef PRIO1
#undef PRIO0
#undef BAR
#undef VMC4
#undef VMC0
#undef VMC6
}

extern "C" void kernel_launch(void* const* d_in, const int* in_sizes, int n_in,
                              void* d_out, int out_size, void* d_ws, size_t ws_size,
                              hipStream_t stream) {
  const float* x    = (const float*)d_in[0];
  const int*   qw   = (const int*)d_in[1];
  const float* lut  = (const float*)d_in[2];
  const float* bias = (const float*)d_in[3];

  __bf16* Wb = (__bf16*)d_ws;
  __bf16* Xb = (__bf16*)((char*)d_ws + (size_t)N_DIM * K_DIM * 2);

  {
    int total = N_DIM * (K_DIM / 32);
    anyprec_dequant_kernel<<<total / 256, 256, 0, stream>>>(qw, lut, Wb);
  }
  {
    int n8 = (M_DIM * K_DIM) / 8;
    cvt_x_kernel<<<(n8 + 255) / 256, 256, 0, stream>>>(x, Xb, n8);
  }
  {
    dim3 grid((M_DIM / 256) * (N_DIM / 256));  // 32*16 = 512
    anyprec_gemm_kernel<<<grid, 512, 0, stream>>>(Xb, Wb, bias, (float*)d_out);
  }
}

// Round 8
// 264.297 us; speedup vs baseline: 1.1070x; 1.1070x over previous
//
#include <hip/hip_runtime.h>
#include <hip/hip_bf16.h>
#include <stdint.h>

#define M_DIM 8192   // 4*2048
#define N_DIM 4096   // OUT_FEATURES
#define K_DIM 4096   // IN_FEATURES
#define KB2   (K_DIM * 2)   // bytes per K-row

typedef __attribute__((ext_vector_type(8))) __bf16 bf16x8;
typedef __attribute__((ext_vector_type(4))) float  f32x4;

#define GLD_LDS16(gaddr, laddr)                                            \
  __builtin_amdgcn_global_load_lds(                                        \
      (const __attribute__((address_space(1))) uint32_t*)(gaddr),          \
      (__attribute__((address_space(3))) uint32_t*)(laddr), 16, 0, 0)

// ---------------------------------------------------------------------------
// Dequant: qweight (8, O, 128) int32 bit-planes + lut (O,16) -> Wb (O,K) bf16
// ---------------------------------------------------------------------------
__global__ __launch_bounds__(256) void anyprec_dequant_kernel(
    const int* __restrict__ q, const float* __restrict__ lut,
    __bf16* __restrict__ Wb) {
  int t = blockIdx.x * 256 + threadIdx.x;   // 0 .. O*128-1
  int o = t >> 7;
  int w = t & 127;
  const int PLANE = N_DIM * (K_DIM / 32);
  int base = o * (K_DIM / 32) + w;
  uint32_t q0 = (uint32_t)q[0 * PLANE + base];
  uint32_t q1 = (uint32_t)q[1 * PLANE + base];
  uint32_t q2 = (uint32_t)q[2 * PLANE + base];
  uint32_t q3 = (uint32_t)q[3 * PLANE + base];
  const float* lrow = lut + o * 16;

  __bf16 vals[32];
#pragma unroll
  for (int i = 0; i < 32; ++i) {
    uint32_t idx = ((q0 >> i) & 1u) | (((q1 >> i) & 1u) << 1) |
                   (((q2 >> i) & 1u) << 2) | (((q3 >> i) & 1u) << 3);
    vals[i] = (__bf16)lrow[idx];
  }
  bf16x8* dst = (bf16x8*)(Wb + (size_t)o * K_DIM + w * 32);
#pragma unroll
  for (int r = 0; r < 4; ++r) {
    bf16x8 v;
#pragma unroll
    for (int j = 0; j < 8; ++j) v[j] = vals[r * 8 + j];
    dst[r] = v;
  }
}

// ---------------------------------------------------------------------------
// x fp32 -> bf16
// ---------------------------------------------------------------------------
__global__ __launch_bounds__(256) void cvt_x_kernel(
    const float* __restrict__ x, __bf16* __restrict__ xb, int n8) {
  int t = blockIdx.x * 256 + threadIdx.x;
  if (t >= n8) return;
  f32x4 a = ((const f32x4*)x)[t * 2];
  f32x4 b = ((const f32x4*)x)[t * 2 + 1];
  bf16x8 v;
  v[0] = (__bf16)a[0]; v[1] = (__bf16)a[1]; v[2] = (__bf16)a[2]; v[3] = (__bf16)a[3];
  v[4] = (__bf16)b[0]; v[5] = (__bf16)b[1]; v[6] = (__bf16)b[2]; v[7] = (__bf16)b[3];
  ((bf16x8*)xb)[t] = v;
}

// ---------------------------------------------------------------------------
// 256x256 bf16 GEMM, 8-phase register-pipelined (R8 = R5 + COLLECTIVE certs).
// Certification rule: vmcnt(N) goes BEFORE a barrier (wave waits own loads,
// barrier makes it collective); dependent ds_reads only in later phases.
// Certs at end-p3/end-p7 (vmcnt(4)); reg prefetch of next tile at p4/p8.
// Stage slots: p1=B0(O) p2=A0(E+2) p3=B1(E+2) p4=A1(E+2)
//              p5=B0(E+2) p6=A0(O+2) p7=B1(O+2) p8=A1(O+2)
// ---------------------------------------------------------------------------
__global__ __launch_bounds__(512, 2) void anyprec_gemm_kernel(
    const __bf16* __restrict__ A,   // M x K bf16
    const __bf16* __restrict__ B,   // N x K bf16
    const float* __restrict__ bias,
    float* __restrict__ C) {
  __shared__ __bf16 lds[2][2][2][128 * 64];   // 131072 B

  // XCD-aware bijective swizzle (512 wgs, 512%8==0)
  int bid = blockIdx.x;
  int swz = (bid & 7) * 64 + (bid >> 3);
  int mb = swz >> 4;    // 32 m-tiles
  int nb = swz & 15;    // 16 n-tiles

  const int tid  = threadIdx.x;
  const int lane = tid & 63;
  const int wid  = tid >> 6;
  const int wr   = wid >> 2;   // 0..1
  const int wc   = wid & 3;    // 0..3

  const char* gA = (const char*)A + (size_t)mb * 256 * KB2;
  const char* gB = (const char*)B + (size_t)nb * 256 * KB2;
  const size_t gro0 = (size_t)(tid >> 3) * KB2;       // row  = chunk>>3
  const size_t gro1 = gro0 + (size_t)64 * KB2;        // row + 64
  const int    scx  = (((tid & 7) ^ ((tid >> 3) & 7)) << 4);  // swizzled src chunk
  const int    lt0  = tid * 16;
  const int    lt1  = tid * 16 + 8192;

  const int aoff0 = (wr * 64 + (lane & 15)) * 128;
  const int boff0 = (wc * 32 + (lane & 15)) * 128;
  const int kko0  = (((lane >> 4)) ^ (lane & 7)) << 4;
  const int kko1  = ((4 + (lane >> 4)) ^ (lane & 7)) << 4;

  f32x4 acc[2][2][4][2];
#pragma unroll
  for (int qm = 0; qm < 2; ++qm)
#pragma unroll
    for (int qn = 0; qn < 2; ++qn)
#pragma unroll
      for (int mf = 0; mf < 4; ++mf)
#pragma unroll
        for (int nf = 0; nf < 2; ++nf) acc[qm][qn][mf][nf] = (f32x4)0.0f;

  bf16x8 a0[4][2], a1[4][2], b0[2][2], b1[2][2];

#define STAGE(mat, h, buf, t) {                                            \
    char* lb_ = (char*)&lds[buf][mat][h][0];                               \
    const char* gb_ = (mat ? gB : gA) + (size_t)(h) * 128 * KB2            \
                      + (size_t)(t) * 128;                                 \
    GLD_LDS16(gb_ + gro0 + scx, lb_ + lt0);                                \
    GLD_LDS16(gb_ + gro1 + scx, lb_ + lt1); }

#define LDA(dst, qm, buf) {                                                \
    const char* p_ = (const char*)&lds[buf][0][qm][0] + aoff0;             \
    _Pragma("unroll")                                                      \
    for (int mf = 0; mf < 4; ++mf) {                                       \
      dst[mf][0] = *(const bf16x8*)(p_ + mf * 2048 + kko0);                \
      dst[mf][1] = *(const bf16x8*)(p_ + mf * 2048 + kko1); } }

#define LDB(dst, qn, buf) {                                                \
    const char* p_ = (const char*)&lds[buf][1][qn][0] + boff0;             \
    _Pragma("unroll")                                                      \
    for (int nf = 0; nf < 2; ++nf) {                                       \
      dst[nf][0] = *(const bf16x8*)(p_ + nf * 2048 + kko0);                \
      dst[nf][1] = *(const bf16x8*)(p_ + nf * 2048 + kko1); } }

#define MMA(qm, qn, aa, bb) {                                              \
    _Pragma("unroll")                                                      \
    for (int mf = 0; mf < 4; ++mf)                                         \
      _Pragma("unroll")                                                    \
      for (int nf = 0; nf < 2; ++nf) {                                     \
        acc[qm][qn][mf][nf] = __builtin_amdgcn_mfma_f32_16x16x32_bf16(     \
            aa[mf][0], bb[nf][0], acc[qm][qn][mf][nf], 0, 0, 0);           \
        acc[qm][qn][mf][nf] = __builtin_amdgcn_mfma_f32_16x16x32_bf16(     \
            aa[mf][1], bb[nf][1], acc[qm][qn][mf][nf], 0, 0, 0); } }

#define PRIO1 __builtin_amdgcn_s_setprio(1);
#define PRIO0 __builtin_amdgcn_s_setprio(0);
#define BAR   __builtin_amdgcn_s_barrier();
#define VMC(n) asm volatile("s_waitcnt vmcnt(" #n ")" ::: "memory");

  // ---- prologue: stage tile0 + A0,B1,A1 of tile1; collective-cert tile0
  STAGE(0, 0, 0, 0);  // A0(0)
  STAGE(1, 0, 0, 0);  // B0(0)
  STAGE(1, 1, 0, 0);  // B1(0)
  STAGE(0, 1, 0, 0);  // A1(0)
  STAGE(0, 0, 1, 1);  // A0(1)
  STAGE(1, 1, 1, 1);  // B1(1)
  STAGE(0, 1, 1, 1);  // A1(1)
  VMC(6); BAR;        // tile0 certified for ALL waves
  LDA(a0, 0, 0); LDB(b0, 0, 0);   // consumed in p1

  // ---- main loop: tiles E=2i (buf0), O=2i+1 (buf1), i = 0..30
  for (int i = 0; i < 31; ++i) {
    const int t1 = 2 * i + 1, t2 = 2 * i + 2, t3 = 2 * i + 3;
    // p1: MMA(0,0)E ; load B1(E) ; stage B0(O)
    STAGE(1, 0, 1, t1);
    PRIO1; LDB(b1, 1, 0); MMA(0, 0, a0, b0); PRIO0; BAR;
    // p2: MMA(0,1)E ; load A1(E) ; stage A0(E+2)
    STAGE(0, 0, 0, t2);
    PRIO1; LDA(a1, 1, 0); MMA(0, 1, a0, b1); PRIO0; BAR;
    // p3: MMA(1,1)E ; stage B1(E+2) ; COLLECTIVE cert of tile O at end
    STAGE(1, 1, 0, t2);
    PRIO1; MMA(1, 1, a1, b1); PRIO0; VMC(4); BAR;
    // p4: MMA(1,0)E ; load A0(O), B0(O) (certified) ; stage A1(E+2)
    STAGE(0, 1, 0, t2);
    PRIO1; LDA(a0, 0, 1); MMA(1, 0, a1, b0); LDB(b0, 0, 1); PRIO0; BAR;
    // p5: MMA(0,0)O ; load B1(O) ; stage B0(E+2)
    STAGE(1, 0, 0, t2);
    PRIO1; LDB(b1, 1, 1); MMA(0, 0, a0, b0); PRIO0; BAR;
    // p6: MMA(0,1)O ; load A1(O) ; stage A0(O+2)
    STAGE(0, 0, 1, t3);
    PRIO1; LDA(a1, 1, 1); MMA(0, 1, a0, b1); PRIO0; BAR;
    // p7: MMA(1,1)O ; stage B1(O+2) ; COLLECTIVE cert of tile E+2 at end
    STAGE(1, 1, 1, t3);
    PRIO1; MMA(1, 1, a1, b1); PRIO0; VMC(4); BAR;
    // p8: MMA(1,0)O ; load A0(E+2), B0(E+2) (certified) ; stage A1(O+2)
    STAGE(0, 1, 1, t3);
    PRIO1; LDA(a0, 0, 0); MMA(1, 0, a1, b0); LDB(b0, 0, 0); PRIO0; BAR;
  }

  // ---- tail: tiles 62 (buf0), 63 (buf1); regs hold a0,b0 of 62;
  //      outstanding stages: A0(63),B1(63),A1(63)
  STAGE(1, 0, 1, 63);                         // B0(63)
  PRIO1; LDB(b1, 1, 0); MMA(0, 0, a0, b0); PRIO0; BAR;
  PRIO1; LDA(a1, 1, 0); MMA(0, 1, a0, b1); PRIO0; BAR;
  PRIO1; MMA(1, 1, a1, b1); PRIO0; VMC(0); BAR;   // tile 63 collective-certified
  PRIO1; LDA(a0, 0, 1); MMA(1, 0, a1, b0); LDB(b0, 0, 1); PRIO0; BAR;
  PRIO1; LDB(b1, 1, 1); MMA(0, 0, a0, b0); PRIO0; BAR;
  PRIO1; LDA(a1, 1, 1); MMA(0, 1, a0, b1); PRIO0; BAR;
  MMA(1, 1, a1, b1);
  MMA(1, 0, a1, b0);

  // ---- epilogue: C/D layout col=lane&15, row=(lane>>4)*4+j
  const int cL = lane & 15;
  const int rL = (lane >> 4) * 4;
#pragma unroll
  for (int qn = 0; qn < 2; ++qn)
#pragma unroll
    for (int nf = 0; nf < 2; ++nf) {
      int col = nb * 256 + qn * 128 + wc * 32 + nf * 16 + cL;
      float bv = bias[col];
#pragma unroll
      for (int qm = 0; qm < 2; ++qm)
#pragma unroll
        for (int mf = 0; mf < 4; ++mf) {
          int row0 = mb * 256 + qm * 128 + wr * 64 + mf * 16 + rL;
#pragma unroll
          for (int j = 0; j < 4; ++j)
            C[(size_t)(row0 + j) * N_DIM + col] = acc[qm][qn][mf][nf][j] + bv;
        }
    }
#undef STAGE
#undef LDA
#undef LDB
#undef MMA
#undef PRIO1
#undef PRIO0
#undef BAR
#undef VMC
}

extern "C" void kernel_launch(void* const* d_in, const int* in_sizes, int n_in,
                              void* d_out, int out_size, void* d_ws, size_t ws_size,
                              hipStream_t stream) {
  const float* x    = (const float*)d_in[0];
  const int*   qw   = (const int*)d_in[1];
  const float* lut  = (const float*)d_in[2];
  const float* bias = (const float*)d_in[3];

  __bf16* Wb = (__bf16*)d_ws;
  __bf16* Xb = (__bf16*)((char*)d_ws + (size_t)N_DIM * K_DIM * 2);

  {
    int total = N_DIM * (K_DIM / 32);
    anyprec_dequant_kernel<<<total / 256, 256, 0, stream>>>(qw, lut, Wb);
  }
  {
    int n8 = (M_DIM * K_DIM) / 8;
    cvt_x_kernel<<<(n8 + 255) / 256, 256, 0, stream>>>(x, Xb, n8);
  }
  {
    dim3 grid((M_DIM / 256) * (N_DIM / 256));  // 32*16 = 512
    anyprec_gemm_kernel<<<grid, 512, 0, stream>>>(Xb, Wb, bias, (float*)d_out);
  }
}